// Round 1
// baseline (3590.442 us; speedup 1.0000x reference)
//
#include <hip/hip_runtime.h>
#include <cstdint>
#include <cstddef>

// Problem dims
#define VV  32000
#define DD  1024
#define HH  1024
#define LL  2
#define BB  64
#define SS  256
#define G4  4096   // 4*H

typedef __attribute__((ext_vector_type(8))) short short8;
typedef __attribute__((ext_vector_type(4))) float f32x4;
typedef unsigned short u16;
typedef unsigned int u32;

__device__ __forceinline__ u16 f2bf(float f) {
  union { float f; u32 u; } v; v.f = f;
  u32 u = v.u + 0x7fffu + ((v.u >> 16) & 1u);   // RNE
  return (u16)(u >> 16);
}
__device__ __forceinline__ float bf2f(u16 b) {
  union { u32 u; float f; } v; v.u = ((u32)b) << 16;
  return v.f;
}
__device__ __forceinline__ float sigm(float x) { return 1.f / (1.f + __expf(-x)); }
__device__ __forceinline__ float tanh_fast(float x) {
  return 1.f - 2.f / (__expf(2.f * x) + 1.f);
}

// ---------------------------------------------------------------- embed
__global__ void embed_kernel(const int* __restrict__ inputs,
                             const float* __restrict__ emb,
                             u16* __restrict__ x0) {
  int m = blockIdx.x;              // 0..16383, m = s*64 + b
  int s = m >> 6, b = m & 63;
  int tok = inputs[b * SS + s];
  const f32x4* src = (const f32x4*)(emb + (size_t)tok * DD);
  f32x4 v = src[threadIdx.x];
  u32 lo = (u32)f2bf(v[0]) | ((u32)f2bf(v[1]) << 16);
  u32 hi = (u32)f2bf(v[2]) | ((u32)f2bf(v[3]) << 16);
  u32* dst = (u32*)(x0 + (size_t)m * DD + threadIdx.x * 4);
  dst[0] = lo; dst[1] = hi;
}

// ---------------------------------------------------------------- weight permute+transpose+cast
// W_PT[p][k] = bf16(W[k][n]),  n = g*1024+h,  p = h*4+g   (p-rows k-contiguous)
__global__ void permW_kernel(const float* __restrict__ Wx, const float* __restrict__ Wh,
                             u16* __restrict__ WxPT, u16* __restrict__ WhPT) {
  __shared__ float tl[64][65];
  int bid = blockIdx.x;
  int which = bid >> 10;           // 0,1: Wx l0/l1 ; 2,3: Wh l0/l1
  int tile = bid & 1023;
  int ktile = tile >> 6, ntile = tile & 63;
  const float* src = ((which < 2) ? Wx : Wh) + (size_t)(which & 1) * G4 * 1024;
  u16* dst = ((which < 2) ? WxPT : WhPT) + (size_t)(which & 1) * G4 * 1024;
  int tid = threadIdx.x;
  #pragma unroll
  for (int i = 0; i < 16; ++i) {
    int idx = i * 256 + tid;
    int kk = idx >> 6, nn = idx & 63;
    tl[kk][nn] = src[(size_t)(ktile * 64 + kk) * G4 + ntile * 64 + nn];
  }
  __syncthreads();
  #pragma unroll
  for (int i = 0; i < 16; ++i) {
    int idx = i * 256 + tid;
    int nn = idx >> 6, kk = idx & 63;
    int n = ntile * 64 + nn;
    int p = ((n & 1023) << 2) | (n >> 10);
    dst[(size_t)p * 1024 + ktile * 64 + kk] = f2bf(tl[kk][nn]);
  }
}

__global__ void permB_kernel(const float* __restrict__ bb, float* __restrict__ bP) {
  int idx = blockIdx.x * 256 + threadIdx.x;  // 8192
  int l = idx >> 12, p = idx & 4095;
  int h = p >> 2, g = p & 3;
  bP[idx] = bb[l * G4 + g * 1024 + h];
}

// ---------------------------------------------------------------- xg GEMM (m97 structure), layer 0 only
__device__ __forceinline__ void gld_lds16(const void* g, void* l) {
  __builtin_amdgcn_global_load_lds((const __attribute__((address_space(1))) unsigned int*)g,
                                   (__attribute__((address_space(3))) unsigned int*)l, 16, 0, 0);
}

__global__ __launch_bounds__(256) void gemm_xg(
    const u16* __restrict__ A, const u16* __restrict__ W,
    const float* __restrict__ bP, float* Cf, u16* Cb, int out_f32) {
  __shared__ u16 As[128 * 32];
  __shared__ u16 Bs[128 * 32];
  const int tid = threadIdx.x;
  const int wave = tid >> 6, lane = tid & 63;
  const int bid = blockIdx.x;
  const int nt = bid & 31, mt = bid >> 5;     // 32 N-tiles, 128 M-tiles
  const u16* Ap = A + (size_t)mt * 128 * 1024;
  const u16* Wp = W + (size_t)nt * 128 * 1024;
  f32x4 acc[4][4];
  #pragma unroll
  for (int i = 0; i < 4; ++i)
    #pragma unroll
    for (int j = 0; j < 4; ++j) acc[i][j] = (f32x4){0.f, 0.f, 0.f, 0.f};
  const int wm = wave >> 1, wn = wave & 1;
  const int r16 = lane & 15, oct = lane >> 4;
  for (int k0 = 0; k0 < 1024; k0 += 32) {
    #pragma unroll
    for (int issue = 0; issue < 2; ++issue) {
      int cb = issue * 256 + wave * 64;       // wave-uniform chunk base
      int c = cb + lane;                      // 16B chunk id: row=c>>2, kq=c&3
      gld_lds16(Ap + (size_t)(c >> 2) * 1024 + k0 + (c & 3) * 8, As + (size_t)cb * 8);
      gld_lds16(Wp + (size_t)(c >> 2) * 1024 + k0 + (c & 3) * 8, Bs + (size_t)cb * 8);
    }
    asm volatile("s_waitcnt vmcnt(0)" ::: "memory");
    __syncthreads();
    short8 af[4], bfr[4];
    #pragma unroll
    for (int i = 0; i < 4; ++i)
      af[i] = *(const short8*)(As + (wm * 64 + i * 16 + r16) * 32 + oct * 8);
    #pragma unroll
    for (int j = 0; j < 4; ++j)
      bfr[j] = *(const short8*)(Bs + (wn * 64 + j * 16 + r16) * 32 + oct * 8);
    #pragma unroll
    for (int i = 0; i < 4; ++i)
      #pragma unroll
      for (int j = 0; j < 4; ++j)
        acc[i][j] = __builtin_amdgcn_mfma_f32_16x16x32_bf16(af[i], bfr[j], acc[i][j], 0, 0, 0);
    __syncthreads();
  }
  #pragma unroll
  for (int j = 0; j < 4; ++j) {
    int n = nt * 128 + wn * 64 + j * 16 + r16;
    float bias = bP[n];
    #pragma unroll
    for (int i = 0; i < 4; ++i) {
      int m = mt * 128 + wm * 64 + i * 16 + oct * 4;
      #pragma unroll
      for (int r = 0; r < 4; ++r) {
        float val = acc[i][j][r] + bias;
        if (out_f32) Cf[(size_t)(m + r) * G4 + n] = val;
        else         Cb[(size_t)(m + r) * G4 + n] = f2bf(val);
      }
    }
  }
}

// ---------------------------------------------------------------- fused pipelined 2-layer LSTM recurrence
// grid 256 = 4 batch-groups x 64 col-groups; block 512 thr (8 waves).
// Waves 0-3 ("lo"): layer 0 at step s (slot s), Wh0 slice in 128 AGPRs.
// Waves 4-7 ("hi"): layer 1 at step s-1, Wx1+Wh1 slices in 256 AGPRs; its
//   Wx1 A-operand is the SAME LDS h0-tile the lo waves stage (free sharing).
// 257 slots total; one flag array per bg gates both roles (identical
// double-buffer reuse distance as the proven single-layer kernel).
#define STAGE_TILE(HSRC, HADST) do {                                          \
    unsigned long long addr_ = (unsigned long long)((HSRC) + hc_loc * 8);     \
    short8 v0, v1, v2, v3, v4, v5, v6, v7;                                    \
    asm volatile(                                                             \
      "global_load_dwordx4 %0, %8, off sc1\n\t"                               \
      "global_load_dwordx4 %1, %8, off offset:256 sc1\n\t"                    \
      "global_load_dwordx4 %2, %8, off offset:512 sc1\n\t"                    \
      "global_load_dwordx4 %3, %8, off offset:768 sc1\n\t"                    \
      "global_load_dwordx4 %4, %8, off offset:1024 sc1\n\t"                   \
      "global_load_dwordx4 %5, %8, off offset:1280 sc1\n\t"                   \
      "global_load_dwordx4 %6, %8, off offset:1536 sc1\n\t"                   \
      "global_load_dwordx4 %7, %8, off offset:1792 sc1\n\t"                   \
      "s_waitcnt vmcnt(0)"                                                    \
      : "=v"(v0), "=v"(v1), "=v"(v2), "=v"(v3),                               \
        "=v"(v4), "=v"(v5), "=v"(v6), "=v"(v7)                                \
      : "v"(addr_) : "memory");                                               \
    *(short8*)(&(HADST)[b_loc][(hc_loc +   0) * 8]) = v0;                     \
    *(short8*)(&(HADST)[b_loc][(hc_loc +  16) * 8]) = v1;                     \
    *(short8*)(&(HADST)[b_loc][(hc_loc +  32) * 8]) = v2;                     \
    *(short8*)(&(HADST)[b_loc][(hc_loc +  48) * 8]) = v3;                     \
    *(short8*)(&(HADST)[b_loc][(hc_loc +  64) * 8]) = v4;                     \
    *(short8*)(&(HADST)[b_loc][(hc_loc +  80) * 8]) = v5;                     \
    *(short8*)(&(HADST)[b_loc][(hc_loc +  96) * 8]) = v6;                     \
    *(short8*)(&(HADST)[b_loc][(hc_loc + 112) * 8]) = v7;                     \
  } while (0)

__global__ __launch_bounds__(512, 1) void recur2_kernel(
    const u16* __restrict__ Wh0PT,   // [4096][1024]
    const u16* __restrict__ Wx1PT,
    const u16* __restrict__ Wh1PT,
    const float* xgf, const u16* xgb, int xg_f32,   // layer0 xg [16384][4096] (m = t*64+b)
    const float* __restrict__ b1P,   // [4096] permuted layer-1 bias
    const int* __restrict__ lengths,
    u16* __restrict__ h0buf,         // [2][64][1024] bf16
    u16* __restrict__ h1buf,         // [2][64][1024] bf16
    float* __restrict__ x_out,       // [64][256][1024] f32 final output
    float* __restrict__ c0_out, float* __restrict__ h0_out,
    float* __restrict__ c1_out, float* __restrict__ h1_out,
    int* flags) {                    // [4][64]
  __shared__ u16 hA0[16][1032];      // h0 tile (+8 u16 pad) — shared by both roles
  __shared__ u16 hA1[16][1032];      // h1 tile
  __shared__ float gbuf0[16][64];
  __shared__ float gbuf1[16][64];
  __shared__ float xgbuf[16][64];
  __shared__ int len_s[16];
  const int tid = threadIdx.x;
  const int wave = tid >> 6, lane = tid & 63;
  const int bg = blockIdx.x >> 6, cg = blockIdx.x & 63;
  const int r16 = lane & 15, oct = lane >> 4;
  const bool lo = (wave < 4);
  const int wv = wave & 3;

  // B-fragments pinned into AGPRs. lo: bfA=Wh0 (bfB dummy=Wh0); hi: bfA=Wx1, bfB=Wh1.
  short8 bfA[32], bfB[32];
  {
    const u16* rowA = (lo ? Wh0PT : Wx1PT) + (size_t)(cg * 64 + wv * 16 + r16) * 1024 + oct * 8;
    const u16* rowB = (lo ? Wh0PT : Wh1PT) + (size_t)(cg * 64 + wv * 16 + r16) * 1024 + oct * 8;
    #pragma unroll
    for (int kk = 0; kk < 32; ++kk) bfA[kk] = *(const short8*)(rowA + kk * 32);
    #pragma unroll
    for (int kk = 0; kk < 32; ++kk) asm volatile("" : "+a"(bfA[kk]));
    #pragma unroll
    for (int kk = 0; kk < 32; ++kk) bfB[kk] = *(const short8*)(rowB + kk * 32);
    #pragma unroll
    for (int kk = 0; kk < 32; ++kk) asm volatile("" : "+a"(bfB[kk]));
  }
  if (tid < 16) len_s[tid] = lengths[bg * 16 + tid];
  const int th = tid & 255;
  const int b_loc = th >> 4, hc_loc = th & 15;
  const int b_glob = bg * 16 + b_loc;
  const int hc_glob = cg * 16 + hc_loc;
  float c_reg = 0.f, h_reg = 0.f;
  // zero slot-0 of own buffer, coherent (each u32 written once grid-wide per buffer)
  if (!(tid & 1)) {
    u16* zb = lo ? h0buf : h1buf;
    __hip_atomic_store((u32*)(zb + (size_t)b_glob * 1024 + hc_glob), 0u,
                       __ATOMIC_RELAXED, __HIP_MEMORY_SCOPE_AGENT);
  }
  f32x4 bias1 = (f32x4){0.f, 0.f, 0.f, 0.f};
  if (!lo) bias1 = *(const f32x4*)(b1P + hc_glob * 4);

  int* myflags = flags + bg * 64;
  // prefetch xg[0] (lo role)
  f32x4 xg_next = (f32x4){0.f, 0.f, 0.f, 0.f};
  if (lo) {
    size_t xrow = (size_t)b_glob * G4 + cg * 64 + hc_loc * 4;
    if (xg_f32) xg_next = *(const f32x4*)(xgf + xrow);
    else {
      const u16* s = xgb + xrow;
      f32x4 v; v[0] = bf2f(s[0]); v[1] = bf2f(s[1]); v[2] = bf2f(s[2]); v[3] = bf2f(s[3]);
      xg_next = v;
    }
  }

  for (int s = 0; s <= SS; ++s) {
    // ---- group barrier: syncthreads drains end-of-slot-(s-1) sc1 stores,
    // then flag publish + peer poll (sc1 loads see LLC directly)
    __syncthreads();
    if (tid == 0)
      __hip_atomic_store(&myflags[cg], s + 1, __ATOMIC_RELAXED, __HIP_MEMORY_SCOPE_AGENT);
    if (wave == 0) {
      while (__hip_atomic_load(&myflags[lane], __ATOMIC_RELAXED, __HIP_MEMORY_SCOPE_AGENT) < s + 1)
        __builtin_amdgcn_s_sleep(1);
    }
    __syncthreads();
    // ---- stage tiles
    if (lo) {
      // h0 state-after-(s-1): needed by lo MFMA (s<SS) AND hi MFMA (s>=1) — stage always
      const u16* hsrc = h0buf + (size_t)(s & 1) * (BB * 1024) + (size_t)b_glob * 1024;
      STAGE_TILE(hsrc, hA0);
      *(f32x4*)(&xgbuf[b_loc][hc_loc * 4]) = xg_next;
      if (s + 1 < SS) {
        size_t xrow = (size_t)((s + 1) * 64 + b_glob) * G4 + cg * 64 + hc_loc * 4;
        if (xg_f32) xg_next = *(const f32x4*)(xgf + xrow);
        else {
          const u16* sp = xgb + xrow;
          f32x4 v; v[0] = bf2f(sp[0]); v[1] = bf2f(sp[1]); v[2] = bf2f(sp[2]); v[3] = bf2f(sp[3]);
          xg_next = v;
        }
      }
    } else if (s >= 1) {
      // h1 state-after-(s-2)
      const u16* hsrc = h1buf + (size_t)((s - 1) & 1) * (BB * 1024) + (size_t)b_glob * 1024;
      STAGE_TILE(hsrc, hA1);
    }
    __syncthreads();
    // ---- MFMA
    if (lo) {
      if (s < SS) {
        f32x4 acc0 = (f32x4){0.f, 0.f, 0.f, 0.f};
        f32x4 acc1 = (f32x4){0.f, 0.f, 0.f, 0.f};
        #pragma unroll
        for (int kk = 0; kk < 16; ++kk) {
          short8 a0 = *(const short8*)(&hA0[r16][(2 * kk) * 32 + oct * 8]);
          short8 a1 = *(const short8*)(&hA0[r16][(2 * kk + 1) * 32 + oct * 8]);
          acc0 = __builtin_amdgcn_mfma_f32_16x16x32_bf16(a0, bfA[2 * kk], acc0, 0, 0, 0);
          acc1 = __builtin_amdgcn_mfma_f32_16x16x32_bf16(a1, bfA[2 * kk + 1], acc1, 0, 0, 0);
        }
        f32x4 acc = acc0 + acc1;
        #pragma unroll
        for (int r = 0; r < 4; ++r) gbuf0[oct * 4 + r][wv * 16 + r16] = acc[r];
      }
    } else if (s >= 1) {
      f32x4 ax0 = (f32x4){0.f, 0.f, 0.f, 0.f};
      f32x4 ax1 = (f32x4){0.f, 0.f, 0.f, 0.f};
      f32x4 ah0 = (f32x4){0.f, 0.f, 0.f, 0.f};
      f32x4 ah1 = (f32x4){0.f, 0.f, 0.f, 0.f};
      #pragma unroll
      for (int kk = 0; kk < 16; ++kk) {
        short8 a0 = *(const short8*)(&hA0[r16][(2 * kk) * 32 + oct * 8]);
        short8 a1 = *(const short8*)(&hA0[r16][(2 * kk + 1) * 32 + oct * 8]);
        short8 c0 = *(const short8*)(&hA1[r16][(2 * kk) * 32 + oct * 8]);
        short8 c1 = *(const short8*)(&hA1[r16][(2 * kk + 1) * 32 + oct * 8]);
        ax0 = __builtin_amdgcn_mfma_f32_16x16x32_bf16(a0, bfA[2 * kk], ax0, 0, 0, 0);
        ax1 = __builtin_amdgcn_mfma_f32_16x16x32_bf16(a1, bfA[2 * kk + 1], ax1, 0, 0, 0);
        ah0 = __builtin_amdgcn_mfma_f32_16x16x32_bf16(c0, bfB[2 * kk], ah0, 0, 0, 0);
        ah1 = __builtin_amdgcn_mfma_f32_16x16x32_bf16(c1, bfB[2 * kk + 1], ah1, 0, 0, 0);
      }
      f32x4 acc = (ax0 + ax1) + (ah0 + ah1);
      #pragma unroll
      for (int r = 0; r < 4; ++r) gbuf1[oct * 4 + r][wv * 16 + r16] = acc[r];
    }
    __syncthreads();
    // ---- elementwise LSTM cells
    if (lo) {
      if (s < SS) {
        f32x4 g = *(const f32x4*)(&gbuf0[b_loc][hc_loc * 4]);
        f32x4 xv = *(const f32x4*)(&xgbuf[b_loc][hc_loc * 4]);
        float si = sigm(g[0] + xv[0]);
        float sf = sigm(g[1] + xv[1]);
        float gg = tanh_fast(g[2] + xv[2]);
        float so = sigm(g[3] + xv[3]);
        float c_new = sf * c_reg + si * gg;
        float h_new = so * tanh_fast(c_new);
        if (s < len_s[b_loc]) { c_reg = c_new; h_reg = h_new; }
        u32 hb = (u32)f2bf(h_reg);
        u32 nb = (u32)__shfl_xor((int)hb, 1);
        u32 packed = hb | (nb << 16);
        if (!(tid & 1))
          __hip_atomic_store((u32*)(h0buf + (size_t)((s + 1) & 1) * (BB * 1024) +
                                    (size_t)b_glob * 1024 + hc_glob),
                             packed, __ATOMIC_RELAXED, __HIP_MEMORY_SCOPE_AGENT);
      }
    } else if (s >= 1) {
      f32x4 g = *(const f32x4*)(&gbuf1[b_loc][hc_loc * 4]);
      float si = sigm(g[0] + bias1[0]);
      float sf = sigm(g[1] + bias1[1]);
      float gg = tanh_fast(g[2] + bias1[2]);
      float so = sigm(g[3] + bias1[3]);
      float c_new = sf * c_reg + si * gg;
      float h_new = so * tanh_fast(c_new);
      if (s - 1 < len_s[b_loc]) { c_reg = c_new; h_reg = h_new; }
      u32 hb = (u32)f2bf(h_reg);
      u32 nb = (u32)__shfl_xor((int)hb, 1);
      u32 packed = hb | (nb << 16);
      if (!(tid & 1))
        __hip_atomic_store((u32*)(h1buf + (size_t)(s & 1) * (BB * 1024) +
                                  (size_t)b_glob * 1024 + hc_glob),
                           packed, __ATOMIC_RELAXED, __HIP_MEMORY_SCOPE_AGENT);
      __builtin_nontemporal_store(h_reg,
          x_out + (size_t)(b_glob * SS + (s - 1)) * 1024 + hc_glob);
    }
  }
  // finals
  if (lo) {
    c0_out[(size_t)b_glob * 1024 + hc_glob] = c_reg;
    h0_out[(size_t)b_glob * 1024 + hc_glob] = h_reg;
  } else {
    c1_out[(size_t)b_glob * 1024 + hc_glob] = c_reg;
    h1_out[(size_t)b_glob * 1024 + hc_glob] = h_reg;
  }
}

// ---------------------------------------------------------------- launch
extern "C" void kernel_launch(void* const* d_in, const int* in_sizes, int n_in,
                              void* d_out, int out_size, void* d_ws, size_t ws_size,
                              hipStream_t stream) {
  const int* inputs  = (const int*)d_in[0];
  const int* lengths = (const int*)d_in[1];
  const float* emb   = (const float*)d_in[3];
  const float* Wx    = (const float*)d_in[4];
  const float* Wh    = (const float*)d_in[5];
  const float* bb    = (const float*)d_in[6];
  float* out = (float*)d_out;

  char* ws = (char*)d_ws;
  size_t off = 0;
  auto alloc = [&](size_t bytes) -> void* {
    void* p = ws + off;
    off = (off + bytes + 255) & ~(size_t)255;
    return p;
  };
  u16* WxPT = (u16*)alloc((size_t)2 * G4 * 1024 * 2);
  u16* WhPT = (u16*)alloc((size_t)2 * G4 * 1024 * 2);
  float* bP = (float*)alloc((size_t)2 * G4 * 4);
  u16* x0   = (u16*)alloc((size_t)16384 * 1024 * 2);
  u16* h0buf = (u16*)alloc((size_t)2 * BB * 1024 * 2);
  u16* h1buf = (u16*)alloc((size_t)2 * BB * 1024 * 2);
  int* flags = (int*)alloc(1024);          // [4 groups][64 blocks]
  size_t xg_f32_bytes = (size_t)16384 * G4 * 4;
  int xg_f32 = (ws_size > off) && ((ws_size - off) >= xg_f32_bytes);
  float* xgf = (float*)(ws + off);
  u16* xgb   = (u16*)(ws + off);

  hipMemsetAsync(flags, 0, 1024, stream);
  embed_kernel<<<dim3(16384), dim3(256), 0, stream>>>(inputs, emb, x0);
  permW_kernel<<<dim3(4096), dim3(256), 0, stream>>>(Wx, Wh, WxPT, WhPT);
  permB_kernel<<<dim3(32), dim3(256), 0, stream>>>(bb, bP);

  // layer-0 input projection only (layer-1's is fused into the recurrence)
  gemm_xg<<<dim3(4096), dim3(256), 0, stream>>>(x0, WxPT, bP, xgf, xgb, xg_f32);

  float* cs_base = out + (size_t)BB * SS * HH;
  float* hs_base = cs_base + (size_t)LL * BB * HH;

  const u16* Wh0 = WhPT;
  const u16* Wx1 = WxPT + (size_t)G4 * 1024;
  const u16* Wh1 = WhPT + (size_t)G4 * 1024;
  const float* b1 = bP + G4;
  const float* xgf_c = xgf;
  const u16* xgb_c = xgb;
  float* c0_out = cs_base;
  float* c1_out = cs_base + (size_t)BB * HH;
  float* h0_out = hs_base;
  float* h1_out = hs_base + (size_t)BB * HH;
  void* args[] = { (void*)&Wh0, (void*)&Wx1, (void*)&Wh1,
                   (void*)&xgf_c, (void*)&xgb_c, (void*)&xg_f32,
                   (void*)&b1, (void*)&lengths,
                   (void*)&h0buf, (void*)&h1buf, (void*)&out,
                   (void*)&c0_out, (void*)&h0_out,
                   (void*)&c1_out, (void*)&h1_out,
                   (void*)&flags };
  hipLaunchCooperativeKernel((void*)recur2_kernel, dim3(256), dim3(512), args, 0, stream);
}